// Round 7
// baseline (206.979 us; speedup 1.0000x reference)
//
#include <hip/hip_runtime.h>

// AdaptiveDecayMemory: out = ((Q K^T * scale) ∘ W_decay) V Wo^T * out_scale
// B=4, T=2048, D=1024.  bf16 MFMA, fp32 accum.
// Single GEMM template gemmX: 256x256 tile, 8 waves (2Mx4N, wave=128x64 ->
// 24 ds_read_b128 per 64 MFMA per wave), BK=64, 2x64KB LDS dbuf,
// ONE barrier + vmcnt(0) per K-tile, XCD-swizzled grid.
// R uses split-K (partial f32) so no block exceeds 16 serial K-tiles.

using u16 = unsigned short;
typedef __bf16 bf16x8 __attribute__((ext_vector_type(8)));
typedef float f32x4 __attribute__((ext_vector_type(4)));

__device__ inline u16 f2bf(float f) {
  unsigned u = __builtin_bit_cast(unsigned, f);
  unsigned r = (u + 0x7FFFu + ((u >> 16) & 1u)) >> 16;   // RNE
  return (u16)r;
}

__device__ inline void gload16(const u16* g, u16* l) {
  __builtin_amdgcn_global_load_lds(
      (const __attribute__((address_space(1))) void*)g,
      (__attribute__((address_space(3))) void*)l, 16, 0, 0);
}

// bijective XCD swizzle (m204): contiguous chunk of grid per XCD
__device__ __forceinline__ int xcd_swz(int o, int n) {
  int q = n >> 3, r = n & 7;
  int xcd = o & 7, slot = o >> 3;
  return (xcd < r ? xcd * (q + 1) : r * (q + 1) + (xcd - r) * q) + slot;
}

// ---------- fused x cast (fp32->bf16) + decay logit GEMV ----------
__global__ __launch_bounds__(256) void xcast_decay(const float* __restrict__ x,
    u16* __restrict__ Xbf, const float* __restrict__ Wd,
    const float* __restrict__ bd, float* __restrict__ ldec) {
  int row = blockIdx.x;
  int t = threadIdx.x;
  float4 f = reinterpret_cast<const float4*>(x + (size_t)row * 1024)[t];
  float4 g = reinterpret_cast<const float4*>(Wd)[t];
  ushort4 o;
  o.x = f2bf(f.x); o.y = f2bf(f.y); o.z = f2bf(f.z); o.w = f2bf(f.w);
  reinterpret_cast<ushort4*>(Xbf + (size_t)row * 1024)[t] = o;
  float s = f.x * g.x + f.y * g.y + f.z * g.z + f.w * g.w;
  #pragma unroll
  for (int off = 32; off > 0; off >>= 1) s += __shfl_xor(s, off);
  __shared__ float red[4];
  if ((t & 63) == 0) red[t >> 6] = s;
  __syncthreads();
  if (t == 0) {
    float tot = red[0] + red[1] + red[2] + red[3];
    float dec = 1.f / (1.f + expf(-(tot + bd[0])));
    ldec[row] = logf(dec + 1e-8f);
  }
}

// ---------- weight cast ----------
__global__ __launch_bounds__(256) void wcast(const float* __restrict__ Wq,
    const float* __restrict__ Wk, const float* __restrict__ Wv,
    const float* __restrict__ Wo, u16* __restrict__ Wall) {
  int b = blockIdx.x;
  int m = b >> 10;
  const float* src = (m == 0) ? Wq : (m == 1) ? Wk : (m == 2) ? Wv : Wo;
  int i = ((b & 1023) * 256 + threadIdx.x) * 4;
  float4 f = *reinterpret_cast<const float4*>(src + i);
  ushort4 o;
  o.x = f2bf(f.x); o.y = f2bf(f.y); o.z = f2bf(f.z); o.w = f2bf(f.w);
  *reinterpret_cast<ushort4*>(Wall + (size_t)m * 1048576 + i) = o;
}

// ---------- R partial merge: R[rows 0..1023 per batch] = bf16(p0 + p1) ----------
__global__ __launch_bounds__(256) void radd(const float* __restrict__ p0,
    const float* __restrict__ p1, u16* __restrict__ R) {
  size_t i = ((size_t)blockIdx.x * 256 + threadIdx.x) * 4;   // 4.19M elems total
  float4 a = *reinterpret_cast<const float4*>(p0 + i);
  float4 b = *reinterpret_cast<const float4*>(p1 + i);
  size_t batch = i >> 20, within = i & 1048575;
  ushort4 o;
  o.x = f2bf(a.x + b.x); o.y = f2bf(a.y + b.y);
  o.z = f2bf(a.z + b.z); o.w = f2bf(a.w + b.w);
  *reinterpret_cast<ushort4*>(R + batch * 2097152 + within) = o;
}

// ---------- gemmX: 256x256, BK=64, wave 128x64 ----------
// C[m,n] = sum_k A[m,k]*B[n,k]  (both K-contiguous).
// MODE 0: plain, bf16 out.        MODE 1: S (tri grid, decay epi -> bf16).
// MODE 2: R split-K (f32 partials for it<4, bf16 direct for it>=4).
// MODE 3: plain, f32 * scale out.
template <int MODE>
__global__ __launch_bounds__(512, 1)
void gemmX(const u16* __restrict__ Ab, const u16* __restrict__ Bb,
           void* __restrict__ Cv, int lda, int ldb, int ldc, int K,
           int tiles_n, const float* __restrict__ ldec,
           const float* __restrict__ scale_ptr,
           float* __restrict__ aux0, float* __restrict__ aux1,
           long long abs_, long long bbs_, long long cbs_) {
  __shared__ __align__(16) u16 lds2[65536];   // 2 bufs x (A 32KB | B 32KB)

  const int batch = blockIdx.y;
  const u16* A = Ab + (size_t)batch * abs_;
  const u16* B = Bb + (size_t)batch * bbs_;

  const int bx = xcd_swz(blockIdx.x, gridDim.x);
  int it, jt, kt0, kend, ks = 0; bool part = false;
  if (MODE == 0 || MODE == 3) {
    it = bx / tiles_n; jt = bx % tiles_n; kt0 = 0; kend = K / 64;
  } else if (MODE == 1) {
    int L = bx; it = 0;
    while (L >= 8 - it) { L -= 8 - it; ++it; }
    jt = it + L; kt0 = 0; kend = 16;
  } else {   // MODE 2: R, K=2048 (32 K-tiles), kt0 = 4*it (upper-tri S)
    if (bx < 32) {
      it = bx >> 3; jt = (bx >> 1) & 3; ks = bx & 1; part = true;
      kt0 = ks ? 16 : it * 4; kend = ks ? 32 : 16;
    } else {
      int z = bx - 32; it = 4 + (z >> 2); jt = z & 3;
      kt0 = it * 4; kend = 32;
    }
  }
  const int m0 = it * 256, n0 = jt * 256;

  const int tid = threadIdx.x;
  const int lane = tid & 63;
  const int w = tid >> 6;                 // 0..7
  const int wm = w >> 2, wn = w & 3;      // wave tile: rows wm*128, cols wn*64
  const int l15 = lane & 15, lhi = lane >> 4;
  const int l8 = lane >> 3;
  const int gch = (lane & 7) ^ (l8 & 7);  // pre-swizzled source chunk (rule #21)

  f32x4 acc[8][4];
  #pragma unroll
  for (int i = 0; i < 8; ++i)
    #pragma unroll
    for (int j = 0; j < 4; ++j) acc[i][j] = (f32x4)0.f;

  // stage one K-tile: A 256x64 + B 256x64, 8 gloads/thread, linear LDS dest
  auto stage = [&](int kt, int buf) {
    const size_t kb = (size_t)kt * 64 + gch * 8;
    u16* la = &lds2[buf * 16384];
    u16* lb = &lds2[32768 + buf * 16384];
    #pragma unroll
    for (int u = 0; u < 4; ++u)
      gload16(A + (size_t)(m0 + u * 64 + w * 8 + l8) * lda + kb, la + u * 4096 + w * 512);
    #pragma unroll
    for (int u = 0; u < 4; ++u)
      gload16(B + (size_t)(n0 + u * 64 + w * 8 + l8) * ldb + kb, lb + u * 4096 + w * 512);
  };

  stage(kt0, 0);
  asm volatile("s_waitcnt vmcnt(0)" ::: "memory");
  __builtin_amdgcn_s_barrier();

  const int span = kend - kt0;
  for (int t = 0; t < span; ++t) {
    const int buf = t & 1;
    if (t + 1 < span) stage(kt0 + t + 1, buf ^ 1);   // issue early, land late

    const u16* baseA = &lds2[buf * 16384];
    const u16* baseB = &lds2[32768 + buf * 16384];

    bf16x8 bv[4][2];
    #pragma unroll
    for (int ni = 0; ni < 4; ++ni) {
      int r = wn * 64 + ni * 16 + l15;
      #pragma unroll
      for (int kk = 0; kk < 2; ++kk) {
        int s = (kk * 4 + lhi) ^ (r & 7);
        bv[ni][kk] = *reinterpret_cast<const bf16x8*>(&baseB[r * 64 + s * 8]);
      }
    }
    __builtin_amdgcn_s_setprio(1);
    #pragma unroll
    for (int mi = 0; mi < 8; ++mi) {
      int r = wm * 128 + mi * 16 + l15;
      int s0 = lhi ^ (r & 7), s1 = (4 + lhi) ^ (r & 7);
      bf16x8 a0 = *reinterpret_cast<const bf16x8*>(&baseA[r * 64 + s0 * 8]);
      bf16x8 a1 = *reinterpret_cast<const bf16x8*>(&baseA[r * 64 + s1 * 8]);
      #pragma unroll
      for (int ni = 0; ni < 4; ++ni)
        acc[mi][ni] = __builtin_amdgcn_mfma_f32_16x16x32_bf16(a0, bv[ni][0], acc[mi][ni], 0, 0, 0);
      #pragma unroll
      for (int ni = 0; ni < 4; ++ni)
        acc[mi][ni] = __builtin_amdgcn_mfma_f32_16x16x32_bf16(a1, bv[ni][1], acc[mi][ni], 0, 0, 0);
    }
    __builtin_amdgcn_s_setprio(0);
    asm volatile("s_waitcnt vmcnt(0)" ::: "memory");
    __builtin_amdgcn_s_barrier();
  }

  // epilogue: frag (mi,ni) -> row m0+wm*128+mi*16+lhi*4+q, col n0+wn*64+ni*16+l15
  if (MODE == 0) {
    u16* C = (u16*)Cv + (size_t)batch * cbs_;
    #pragma unroll
    for (int mi = 0; mi < 8; ++mi)
      #pragma unroll
      for (int q = 0; q < 4; ++q) {
        int row = m0 + wm * 128 + mi * 16 + lhi * 4 + q;
        u16* crow = C + (size_t)row * ldc + n0 + wn * 64 + l15;
        #pragma unroll
        for (int ni = 0; ni < 4; ++ni) crow[ni * 16] = f2bf(acc[mi][ni][q]);
      }
  } else if (MODE == 1) {
    u16* C = (u16*)Cv + (size_t)batch * cbs_;
    const float* ldp = ldec + (size_t)batch * 2048;
    float ldv[4];
    #pragma unroll
    for (int ni = 0; ni < 4; ++ni) ldv[ni] = ldp[n0 + wn * 64 + ni * 16 + l15];
    const float sc = 0.03125f;   // 1/sqrt(1024)
    #pragma unroll
    for (int mi = 0; mi < 8; ++mi)
      #pragma unroll
      for (int q = 0; q < 4; ++q) {
        int row = m0 + wm * 128 + mi * 16 + lhi * 4 + q;
        u16* crow = C + (size_t)row * ldc + n0 + wn * 64 + l15;
        #pragma unroll
        for (int ni = 0; ni < 4; ++ni) {
          int col = n0 + wn * 64 + ni * 16 + l15;
          int d = col - row;
          float wgt = (d > 0) ? expf(ldv[ni] * (float)(d - 1)) : 0.f;
          crow[ni * 16] = f2bf(acc[mi][ni][q] * sc * wgt);
        }
      }
  } else if (MODE == 2) {
    if (part) {
      float* P = (ks ? aux1 : aux0) + (size_t)batch * 1048576;
      #pragma unroll
      for (int mi = 0; mi < 8; ++mi)
        #pragma unroll
        for (int q = 0; q < 4; ++q) {
          int row = m0 + wm * 128 + mi * 16 + lhi * 4 + q;   // < 1024
          float* crow = P + (size_t)row * 1024 + n0 + wn * 64 + l15;
          #pragma unroll
          for (int ni = 0; ni < 4; ++ni) crow[ni * 16] = acc[mi][ni][q];
        }
    } else {
      u16* C = (u16*)Cv + (size_t)batch * cbs_;
      #pragma unroll
      for (int mi = 0; mi < 8; ++mi)
        #pragma unroll
        for (int q = 0; q < 4; ++q) {
          int row = m0 + wm * 128 + mi * 16 + lhi * 4 + q;
          u16* crow = C + (size_t)row * ldc + n0 + wn * 64 + l15;
          #pragma unroll
          for (int ni = 0; ni < 4; ++ni) crow[ni * 16] = f2bf(acc[mi][ni][q]);
        }
    }
  } else {   // MODE 3
    float* C = (float*)Cv + (size_t)batch * cbs_;
    const float sc = scale_ptr[0];
    #pragma unroll
    for (int mi = 0; mi < 8; ++mi)
      #pragma unroll
      for (int q = 0; q < 4; ++q) {
        int row = m0 + wm * 128 + mi * 16 + lhi * 4 + q;
        float* crow = C + (size_t)row * ldc + n0 + wn * 64 + l15;
        #pragma unroll
        for (int ni = 0; ni < 4; ++ni) crow[ni * 16] = acc[mi][ni][q] * sc;
      }
  }
}

extern "C" void kernel_launch(void* const* d_in, const int* in_sizes, int n_in,
                              void* d_out, int out_size, void* d_ws, size_t ws_size,
                              hipStream_t stream) {
  const float* x   = (const float*)d_in[0];
  const float* Wq  = (const float*)d_in[1];
  const float* Wk  = (const float*)d_in[2];
  const float* Wv  = (const float*)d_in[3];
  const float* Wo  = (const float*)d_in[4];
  const float* Wd  = (const float*)d_in[5];
  const float* bd  = (const float*)d_in[6];
  const float* osc = (const float*)d_in[7];
  float* out = (float*)d_out;

  char* ws = (char*)d_ws;
  size_t off = 0;
  u16* Xbf  = (u16*)(ws + off); off += (size_t)8192 * 1024 * 2;      // 16.78 MB
  u16* Wall = (u16*)(ws + off); off += (size_t)4096 * 1024 * 2;      //  8.39 MB
  u16* VT   = (u16*)(ws + off); off += (size_t)1024 * 8192 * 2;      // 16.78 MB
  u16* S    = (u16*)(ws + off); off += (size_t)4 * 2048 * 2048 * 2;  // 33.55 MB
  float* ldec = (float*)(ws + off); off += (size_t)8192 * 4;
  u16* QK   = (u16*)(ws + off); off += (size_t)8192 * 2048 * 2;      // 33.55 MB
  u16* R    = QK;                               // alias: QK dead once S built
  float* Rp0 = (float*)Xbf;                     // alias: Xbf dead after QK+VT
  float* Rp1 = (float*)((char*)QK + 16777216);  // second half of QK region

  u16* Wqk = Wall;
  u16* Wvb = Wall + 2 * 1048576;
  u16* Wob = Wall + 3 * 1048576;

  // 1) casts + decay
  xcast_decay<<<8192, 256, 0, stream>>>(x, Xbf, Wd, bd, ldec);
  wcast<<<4096, 256, 0, stream>>>(Wq, Wk, Wv, Wo, Wall);

  // 2) QK = Xbf @ Wqk^T  [8192 x 2048]   (256 blocks, 1/CU)
  gemmX<0><<<dim3(256, 1), 512, 0, stream>>>(
      Xbf, Wqk, QK, 1024, 1024, 2048, 1024, 8, nullptr, nullptr, nullptr, nullptr,
      0, 0, 0);

  // 3) VT = Wvb @ Xbf^T  [1024 x 8192]   (128 blocks)
  gemmX<0><<<dim3(128, 1), 512, 0, stream>>>(
      Wvb, Xbf, VT, 1024, 1024, 8192, 1024, 32, nullptr, nullptr, nullptr, nullptr,
      0, 0, 0);

  // 4) S_b = (Q_b K_b^T /32) ∘ weights -> bf16, compact 256² tri grid (144 blocks)
  gemmX<1><<<dim3(36, 4), 512, 0, stream>>>(
      QK, QK + 1024, S, 2048, 2048, 2048, 1024, 0, ldec, nullptr, nullptr, nullptr,
      4194304LL, 4194304LL, 4194304LL);

  // 5) R_b = S_b @ V_b, split-K: it<4 -> f32 partials, it>=4 -> bf16 (192 blocks)
  gemmX<2><<<dim3(48, 4), 512, 0, stream>>>(
      S, VT, R, 2048, 8192, 1024, 2048, 0, nullptr, nullptr, Rp0, Rp1,
      4194304LL, 2048LL, 2097152LL);

  // 5b) merge partials for rows 0..1023 of each batch
  radd<<<4096, 256, 0, stream>>>(Rp0, Rp1, R);

  // 6) out = R @ Wo^T * out_scale  [8192 x 1024] fp32  (128 blocks)
  gemmX<3><<<dim3(128, 1), 512, 0, stream>>>(
      R, Wob, out, 1024, 1024, 1024, 1024, 4, nullptr, osc, nullptr, nullptr,
      0, 0, 0);
}

// Round 8
// 201.956 us; speedup vs baseline: 1.0249x; 1.0249x over previous
//
#include <hip/hip_runtime.h>

// AdaptiveDecayMemory: out = ((Q K^T * scale) ∘ W_decay) V Wo^T * out_scale
// B=4, T=2048, D=1024.  bf16 MFMA, fp32 accum.
// gemm6: 256x128 tile, 8 waves (4Mx2N, wave 64x64), BK=32,
//   6-buffer LDS rotation (144 KiB), UNROLL-2: one barrier per 2 K-steps,
//   stage steps (t+4,t+5) per iter -> full-iteration latency cover,
//   counted vmcnt(6) (never 0 in loop).  XCD-swizzled grids.
// R split-K caps every block at 16 iters (f32 partials + radd merge).

using u16 = unsigned short;
typedef __bf16 bf16x8 __attribute__((ext_vector_type(8)));
typedef float f32x4 __attribute__((ext_vector_type(4)));

__device__ inline u16 f2bf(float f) {
  unsigned u = __builtin_bit_cast(unsigned, f);
  unsigned r = (u + 0x7FFFu + ((u >> 16) & 1u)) >> 16;   // RNE
  return (u16)r;
}

__device__ inline void gload16(const u16* g, u16* l) {
  __builtin_amdgcn_global_load_lds(
      (const __attribute__((address_space(1))) void*)g,
      (__attribute__((address_space(3))) void*)l, 16, 0, 0);
}

// bijective XCD swizzle (m204)
__device__ __forceinline__ int xcd_swz(int o, int n) {
  int q = n >> 3, r = n & 7;
  int xcd = o & 7, slot = o >> 3;
  return (xcd < r ? xcd * (q + 1) : r * (q + 1) + (xcd - r) * q) + slot;
}

// ---------- fused x cast (fp32->bf16) + decay logit GEMV ----------
__global__ __launch_bounds__(256) void xcast_decay(const float* __restrict__ x,
    u16* __restrict__ Xbf, const float* __restrict__ Wd,
    const float* __restrict__ bd, float* __restrict__ ldec) {
  int row = blockIdx.x;
  int t = threadIdx.x;
  float4 f = reinterpret_cast<const float4*>(x + (size_t)row * 1024)[t];
  float4 g = reinterpret_cast<const float4*>(Wd)[t];
  ushort4 o;
  o.x = f2bf(f.x); o.y = f2bf(f.y); o.z = f2bf(f.z); o.w = f2bf(f.w);
  reinterpret_cast<ushort4*>(Xbf + (size_t)row * 1024)[t] = o;
  float s = f.x * g.x + f.y * g.y + f.z * g.z + f.w * g.w;
  #pragma unroll
  for (int off = 32; off > 0; off >>= 1) s += __shfl_xor(s, off);
  __shared__ float red[4];
  if ((t & 63) == 0) red[t >> 6] = s;
  __syncthreads();
  if (t == 0) {
    float tot = red[0] + red[1] + red[2] + red[3];
    float dec = 1.f / (1.f + expf(-(tot + bd[0])));
    ldec[row] = logf(dec + 1e-8f);
  }
}

// ---------- weight cast ----------
__global__ __launch_bounds__(256) void wcast(const float* __restrict__ Wq,
    const float* __restrict__ Wk, const float* __restrict__ Wv,
    const float* __restrict__ Wo, u16* __restrict__ Wall) {
  int b = blockIdx.x;
  int m = b >> 10;
  const float* src = (m == 0) ? Wq : (m == 1) ? Wk : (m == 2) ? Wv : Wo;
  int i = ((b & 1023) * 256 + threadIdx.x) * 4;
  float4 f = *reinterpret_cast<const float4*>(src + i);
  ushort4 o;
  o.x = f2bf(f.x); o.y = f2bf(f.y); o.z = f2bf(f.z); o.w = f2bf(f.w);
  *reinterpret_cast<ushort4*>(Wall + (size_t)m * 1048576 + i) = o;
}

// ---------- R partial merge ----------
__global__ __launch_bounds__(256) void radd(const float* __restrict__ p0,
    const float* __restrict__ p1, u16* __restrict__ R) {
  size_t i = ((size_t)blockIdx.x * 256 + threadIdx.x) * 4;
  float4 a = *reinterpret_cast<const float4*>(p0 + i);
  float4 b = *reinterpret_cast<const float4*>(p1 + i);
  size_t batch = i >> 20, within = i & 1048575;
  ushort4 o;
  o.x = f2bf(a.x + b.x); o.y = f2bf(a.y + b.y);
  o.z = f2bf(a.z + b.z); o.w = f2bf(a.w + b.w);
  *reinterpret_cast<ushort4*>(R + batch * 2097152 + within) = o;
}

// ---------- gemm6: 256x128, BK=32, 6-buf, unroll-2 ----------
// C[m,n] = sum_k A[m,k]*B[n,k]  (both K-contiguous).
// MODE 0: plain bf16.  MODE 1: S tri grid + decay epi.  MODE 2: R split-K.
// MODE 3: f32 * scale.
// LDS buf = 24KB: A 256x32 (16KB) | B 128x32 (8KB).  3 gloads/thread/step.
// Chunk swizzle: slot (row, p) holds global chunk p ^ ((row>>1)&3).
template <int MODE>
__global__ __launch_bounds__(512, 1)
void gemm6(const u16* __restrict__ Ab, const u16* __restrict__ Bb,
           void* __restrict__ Cv, int lda, int ldb, int ldc, int K,
           int tiles_n, const float* __restrict__ ldec,
           const float* __restrict__ scale_ptr,
           float* __restrict__ aux0, float* __restrict__ aux1,
           long long abs_, long long bbs_, long long cbs_) {
  __shared__ __align__(16) u16 lds6[73728];   // 6 x 12288 u16 = 144 KiB

  const int batch = blockIdx.y;
  const u16* A = Ab + (size_t)batch * abs_;
  const u16* B = Bb + (size_t)batch * bbs_;

  const int bx = xcd_swz(blockIdx.x, gridDim.x);
  int it, jt, kt0, kend, ks = 0; bool part = false;
  if (MODE == 0 || MODE == 3) {
    it = bx / tiles_n; jt = bx % tiles_n; kt0 = 0; kend = K / 32;
  } else if (MODE == 1) {                      // S: 72 live tiles, jt >= 2*it
    int L = bx; it = 0;
    while (L >= 16 - 2 * it) { L -= 16 - 2 * it; ++it; }
    jt = 2 * it + L; kt0 = 0; kend = 32;
  } else {                                     // R: K=2048 -> 64 steps
    if (bx < 64) {
      it = bx >> 4; int rm = bx & 15; jt = rm >> 1; ks = rm & 1; part = true;
      kt0 = ks ? 32 : 8 * it; kend = ks ? 64 : 32;
    } else {
      int z = bx - 64; it = 4 + (z >> 3); jt = z & 7;
      kt0 = 8 * it; kend = 64;
    }
  }
  const int m0 = it * 256, n0 = jt * 128;

  const int tid = threadIdx.x;
  const int lane = tid & 63;
  const int w = tid >> 6;
  const int wm = w >> 1, wn = w & 1;           // wave = 64x64
  const int l15 = lane & 15, lhi = lane >> 4;
  const int sw = (l15 >> 1) & 3;               // read-side row swizzle

  // staging geometry: thread covers (row, phys chunk p=lane&3); logical chunk:
  const int lc = (lane & 3) ^ ((lane >> 3) & 3);
  const int srow = w * 16 + (lane >> 2);       // 0..127
  const int dst = (w * 64 + lane) * 8;         // u16 offset within a region
  const u16* pA0 = A + (size_t)(m0 + srow) * lda + lc * 8;
  const u16* pA1 = A + (size_t)(m0 + 128 + srow) * lda + lc * 8;
  const u16* pB  = B + (size_t)(n0 + srow) * ldb + lc * 8;

  const int steps = kend - kt0;
  const int iters = steps >> 1;                // all spans even

  f32x4 acc[4][4];
  #pragma unroll
  for (int i = 0; i < 4; ++i)
    #pragma unroll
    for (int j = 0; j < 4; ++j) acc[i][j] = (f32x4)0.f;

  auto stage = [&](int ls, int buf) {          // ls: local step (clamped by caller)
    const int ko = (kt0 + ls) * 32;
    u16* lb = &lds6[buf * 12288];
    gload16(pA0 + ko, lb + dst);
    gload16(pA1 + ko, lb + 4096 + dst);
    gload16(pB  + ko, lb + 8192 + dst);
  };

  // prologue: steps 0..3 -> bufs 0..3; drain steps 0,1 (6 = steps 2,3 in flight)
  stage(0, 0); stage(1, 1); stage(2, 2); stage(3, 3);
  asm volatile("s_waitcnt vmcnt(6)" ::: "memory");
  __builtin_amdgcn_s_barrier();

  int b0 = 0, b1 = 1, sb0 = 4, sb1 = 5;
  for (int t = 0; t < iters; ++t) {
    const int ls0 = 2 * t, ls1 = 2 * t + 1;
    const u16* baseA0 = &lds6[b0 * 12288];
    const u16* baseA1 = &lds6[b1 * 12288];

    bf16x8 af0[4], bv0[4], af1[4], bv1[4];
    #pragma unroll
    for (int mi = 0; mi < 4; ++mi) {
      int r = wm * 64 + mi * 16 + l15;
      int p = lhi ^ sw;
      af0[mi] = *reinterpret_cast<const bf16x8*>(&baseA0[r * 32 + p * 8]);
      af1[mi] = *reinterpret_cast<const bf16x8*>(&baseA1[r * 32 + p * 8]);
    }
    #pragma unroll
    for (int ni = 0; ni < 4; ++ni) {
      int r = wn * 64 + ni * 16 + l15;
      int p = lhi ^ sw;
      bv0[ni] = *reinterpret_cast<const bf16x8*>(&baseA0[8192 + r * 32 + p * 8]);
      bv1[ni] = *reinterpret_cast<const bf16x8*>(&baseA1[8192 + r * 32 + p * 8]);
    }

    int s4 = ls0 + 4; if (s4 >= steps) s4 = steps - 1;   // redundant refetch at tail
    int s5 = ls1 + 4; if (s5 >= steps) s5 = steps - 1;
    stage(s4, sb0);
    stage(s5, sb1);

    __builtin_amdgcn_s_setprio(1);
    #pragma unroll
    for (int mi = 0; mi < 4; ++mi)
      #pragma unroll
      for (int ni = 0; ni < 4; ++ni)
        acc[mi][ni] = __builtin_amdgcn_mfma_f32_16x16x32_bf16(
            af0[mi], bv0[ni], acc[mi][ni], 0, 0, 0);
    #pragma unroll
    for (int mi = 0; mi < 4; ++mi)
      #pragma unroll
      for (int ni = 0; ni < 4; ++ni)
        acc[mi][ni] = __builtin_amdgcn_mfma_f32_16x16x32_bf16(
            af1[mi], bv1[ni], acc[mi][ni], 0, 0, 0);
    __builtin_amdgcn_s_setprio(0);

    asm volatile("s_waitcnt vmcnt(6)" ::: "memory");   // drain steps 2t+2,2t+3
    __builtin_amdgcn_s_barrier();

    b0 += 2; if (b0 >= 6) b0 -= 6;
    b1 += 2; if (b1 >= 6) b1 -= 6;
    sb0 += 2; if (sb0 >= 6) sb0 -= 6;
    sb1 += 2; if (sb1 >= 6) sb1 -= 6;
  }
  asm volatile("s_waitcnt vmcnt(0)" ::: "memory");

  // epilogue: frag (mi,ni) -> row m0+wm*64+mi*16+lhi*4+q, col n0+wn*64+ni*16+l15
  if (MODE == 0) {
    u16* C = (u16*)Cv + (size_t)batch * cbs_;
    #pragma unroll
    for (int mi = 0; mi < 4; ++mi)
      #pragma unroll
      for (int q = 0; q < 4; ++q) {
        int row = m0 + wm * 64 + mi * 16 + lhi * 4 + q;
        u16* crow = C + (size_t)row * ldc + n0 + wn * 64 + l15;
        #pragma unroll
        for (int ni = 0; ni < 4; ++ni) crow[ni * 16] = f2bf(acc[mi][ni][q]);
      }
  } else if (MODE == 1) {
    u16* C = (u16*)Cv + (size_t)batch * cbs_;
    const float* ldp = ldec + (size_t)batch * 2048;
    float ldv[4];
    #pragma unroll
    for (int ni = 0; ni < 4; ++ni) ldv[ni] = ldp[n0 + wn * 64 + ni * 16 + l15];
    const float sc = 0.03125f;   // 1/sqrt(1024)
    #pragma unroll
    for (int mi = 0; mi < 4; ++mi)
      #pragma unroll
      for (int q = 0; q < 4; ++q) {
        int row = m0 + wm * 64 + mi * 16 + lhi * 4 + q;
        u16* crow = C + (size_t)row * ldc + n0 + wn * 64 + l15;
        #pragma unroll
        for (int ni = 0; ni < 4; ++ni) {
          int col = n0 + wn * 64 + ni * 16 + l15;
          int d = col - row;
          float wgt = (d > 0) ? expf(ldv[ni] * (float)(d - 1)) : 0.f;
          crow[ni * 16] = f2bf(acc[mi][ni][q] * sc * wgt);
        }
      }
  } else if (MODE == 2) {
    if (part) {
      float* P = (ks ? aux1 : aux0) + (size_t)batch * 1048576;
      #pragma unroll
      for (int mi = 0; mi < 4; ++mi)
        #pragma unroll
        for (int q = 0; q < 4; ++q) {
          int row = m0 + wm * 64 + mi * 16 + lhi * 4 + q;   // < 1024
          float* crow = P + (size_t)row * 1024 + n0 + wn * 64 + l15;
          #pragma unroll
          for (int ni = 0; ni < 4; ++ni) crow[ni * 16] = acc[mi][ni][q];
        }
    } else {
      u16* C = (u16*)Cv + (size_t)batch * cbs_;
      #pragma unroll
      for (int mi = 0; mi < 4; ++mi)
        #pragma unroll
        for (int q = 0; q < 4; ++q) {
          int row = m0 + wm * 64 + mi * 16 + lhi * 4 + q;
          u16* crow = C + (size_t)row * ldc + n0 + wn * 64 + l15;
          #pragma unroll
          for (int ni = 0; ni < 4; ++ni) crow[ni * 16] = f2bf(acc[mi][ni][q]);
        }
    }
  } else {
    float* C = (float*)Cv + (size_t)batch * cbs_;
    const float sc = scale_ptr[0];
    #pragma unroll
    for (int mi = 0; mi < 4; ++mi)
      #pragma unroll
      for (int q = 0; q < 4; ++q) {
        int row = m0 + wm * 64 + mi * 16 + lhi * 4 + q;
        float* crow = C + (size_t)row * ldc + n0 + wn * 64 + l15;
        #pragma unroll
        for (int ni = 0; ni < 4; ++ni) crow[ni * 16] = acc[mi][ni][q] * sc;
      }
  }
}

extern "C" void kernel_launch(void* const* d_in, const int* in_sizes, int n_in,
                              void* d_out, int out_size, void* d_ws, size_t ws_size,
                              hipStream_t stream) {
  const float* x   = (const float*)d_in[0];
  const float* Wq  = (const float*)d_in[1];
  const float* Wk  = (const float*)d_in[2];
  const float* Wv  = (const float*)d_in[3];
  const float* Wo  = (const float*)d_in[4];
  const float* Wd  = (const float*)d_in[5];
  const float* bd  = (const float*)d_in[6];
  const float* osc = (const float*)d_in[7];
  float* out = (float*)d_out;

  char* ws = (char*)d_ws;
  size_t off = 0;
  u16* Xbf  = (u16*)(ws + off); off += (size_t)8192 * 1024 * 2;
  u16* Wall = (u16*)(ws + off); off += (size_t)4096 * 1024 * 2;
  u16* VT   = (u16*)(ws + off); off += (size_t)1024 * 8192 * 2;
  u16* S    = (u16*)(ws + off); off += (size_t)4 * 2048 * 2048 * 2;
  float* ldec = (float*)(ws + off); off += (size_t)8192 * 4;
  u16* QK   = (u16*)(ws + off); off += (size_t)8192 * 2048 * 2;
  u16* R    = QK;                               // alias: QK dead once S built
  float* Rp0 = (float*)Xbf;                     // alias: Xbf dead after QK+VT
  float* Rp1 = (float*)((char*)QK + 16777216);  // 2nd half of QK region

  u16* Wqk = Wall;
  u16* Wvb = Wall + 2 * 1048576;
  u16* Wob = Wall + 3 * 1048576;

  // 1) casts + decay
  xcast_decay<<<8192, 256, 0, stream>>>(x, Xbf, Wd, bd, ldec);
  wcast<<<4096, 256, 0, stream>>>(Wq, Wk, Wv, Wo, Wall);

  // 2) QK = Xbf @ Wqk^T  [8192 x 2048]  (512 blocks, tiles_n=16)
  gemm6<0><<<dim3(512, 1), 512, 0, stream>>>(
      Xbf, Wqk, QK, 1024, 1024, 2048, 1024, 16, nullptr, nullptr, nullptr, nullptr,
      0, 0, 0);

  // 3) VT = Wvb @ Xbf^T  [1024 x 8192]  (256 blocks, tiles_n=64)
  gemm6<0><<<dim3(256, 1), 512, 0, stream>>>(
      Wvb, Xbf, VT, 1024, 1024, 8192, 1024, 64, nullptr, nullptr, nullptr, nullptr,
      0, 0, 0);

  // 4) S_b = (Q_b K_b^T /32) ∘ weights -> bf16, compact tri (72 x 4 blocks)
  gemm6<1><<<dim3(72, 4), 512, 0, stream>>>(
      QK, QK + 1024, S, 2048, 2048, 2048, 1024, 0, ldec, nullptr, nullptr, nullptr,
      4194304LL, 4194304LL, 4194304LL);

  // 5) R_b = S_b @ V_b, split-K for it<4 (96 x 4 blocks), max 16 iters/block
  gemm6<2><<<dim3(96, 4), 512, 0, stream>>>(
      S, VT, R, 2048, 8192, 1024, 2048, 0, nullptr, nullptr, Rp0, Rp1,
      4194304LL, 2048LL, 2097152LL);

  // 5b) merge partials (rows 0..1023 per batch)
  radd<<<4096, 256, 0, stream>>>(Rp0, Rp1, R);

  // 6) out = R @ Wo^T * out_scale  [8192 x 1024] fp32  (256 blocks, tiles_n=8)
  gemm6<3><<<dim3(256, 1), 512, 0, stream>>>(
      R, Wob, out, 1024, 1024, 1024, 1024, 8, nullptr, osc, nullptr, nullptr,
      0, 0, 0);
}

// Round 9
// 164.603 us; speedup vs baseline: 1.2574x; 1.2269x over previous
//
#include <hip/hip_runtime.h>

// AdaptiveDecayMemory: out = ((Q K^T * scale) ∘ W_decay) V Wo^T * out_scale
// B=4, T=2048, D=1024.  bf16 MFMA, fp32 accum.
// gemmP: 128x128 tile, BK=64, 4 waves (wave 64x64), 2x32KB LDS dbuf ->
//   2 blocks/CU co-resident (m114 overlap), counted pipeline:
//   stage(t+1) at top of iter t, vmcnt(0)+barrier at bottom, 1 barrier/iter.
//   r4's proven conflict-free chunk swizzle (slot s holds chunk s^(r&7)).

using u16 = unsigned short;
typedef __bf16 bf16x8 __attribute__((ext_vector_type(8)));
typedef float f32x4 __attribute__((ext_vector_type(4)));

__device__ inline u16 f2bf(float f) {
  unsigned u = __builtin_bit_cast(unsigned, f);
  unsigned r = (u + 0x7FFFu + ((u >> 16) & 1u)) >> 16;   // RNE
  return (u16)r;
}

__device__ inline void gload16(const u16* g, u16* l) {
  __builtin_amdgcn_global_load_lds(
      (const __attribute__((address_space(1))) void*)g,
      (__attribute__((address_space(3))) void*)l, 16, 0, 0);
}

// ---------- merged prep: x cast + decay GEMV  |  weight casts ----------
__global__ __launch_bounds__(256) void prep(const float* __restrict__ x,
    u16* __restrict__ Xbf, const float* __restrict__ Wd,
    const float* __restrict__ bd, float* __restrict__ ldec,
    const float* __restrict__ Wq, const float* __restrict__ Wk,
    const float* __restrict__ Wv, const float* __restrict__ Wo,
    u16* __restrict__ Wall) {
  int b = blockIdx.x;
  int t = threadIdx.x;
  if (b < 8192) {                    // x rows: cast + dot(Wd)
    float4 f = reinterpret_cast<const float4*>(x + (size_t)b * 1024)[t];
    float4 g = reinterpret_cast<const float4*>(Wd)[t];
    ushort4 o;
    o.x = f2bf(f.x); o.y = f2bf(f.y); o.z = f2bf(f.z); o.w = f2bf(f.w);
    reinterpret_cast<ushort4*>(Xbf + (size_t)b * 1024)[t] = o;
    float s = f.x * g.x + f.y * g.y + f.z * g.z + f.w * g.w;
    #pragma unroll
    for (int off = 32; off > 0; off >>= 1) s += __shfl_xor(s, off);
    __shared__ float red[4];
    if ((t & 63) == 0) red[t >> 6] = s;
    __syncthreads();
    if (t == 0) {
      float tot = red[0] + red[1] + red[2] + red[3];
      float dec = 1.f / (1.f + expf(-(tot + bd[0])));
      ldec[b] = logf(dec + 1e-8f);
    }
  } else {                           // weight cast: [Wq;Wk;Wv;Wo]
    int wb = b - 8192;               // 0..4095
    int m = wb >> 10;
    const float* src = (m == 0) ? Wq : (m == 1) ? Wk : (m == 2) ? Wv : Wo;
    int i = ((wb & 1023) * 256 + t) * 4;
    float4 f = *reinterpret_cast<const float4*>(src + i);
    ushort4 o;
    o.x = f2bf(f.x); o.y = f2bf(f.y); o.z = f2bf(f.z); o.w = f2bf(f.w);
    *reinterpret_cast<ushort4*>(Wall + (size_t)m * 1048576 + i) = o;
  }
}

// ---------- gemmP: 128x128, BK=64, 2-buf, 2 blocks/CU ----------
// C[m,n] = sum_k A[m,k]*B[n,k]  (both K-contiguous).
// EPI 0: bf16.  EPI 1: S decay epilogue -> bf16 (skip jt<it).  EPI 2: f32*scale.
// diag=1: kt0 = 2*it (R over upper-tri S).  flip=1: batch>=2 reverses it
// (pairs long/short R spans across dispatch rounds).
template <int EPI>
__global__ __launch_bounds__(256, 2)
void gemmP(const u16* __restrict__ Ab, const u16* __restrict__ Bb,
           void* __restrict__ Cv, int lda, int ldb, int ldc, int K,
           int tiles_n, int diag, int flip, const float* __restrict__ ldec,
           const float* __restrict__ scale_ptr,
           long long abs_, long long bbs_, long long cbs_) {
  __shared__ __align__(16) u16 lds2[32768];   // 2 x (A 16KB | B 16KB) = 64 KiB

  const int batch = blockIdx.y;
  const u16* A = Ab + (size_t)batch * abs_;
  const u16* B = Bb + (size_t)batch * bbs_;

  int it = blockIdx.x / tiles_n;
  const int jt = blockIdx.x % tiles_n;
  if (flip && batch >= 2) it = (gridDim.x / tiles_n - 1) - it;
  if (EPI == 1 && jt < it) return;   // strictly-lower S tiles are zero, never read
  const int m0 = it * 128, n0 = jt * 128;

  const int tid = threadIdx.x;
  const int lane = tid & 63;
  const int w = tid >> 6;                      // 0..3
  const int wm = (w >> 1) * 64, wn = (w & 1) * 64;   // wave = 64x64
  const int l15 = lane & 15, lhi = lane >> 4;
  const int lr8 = lane >> 3;
  const int schunk = (lane & 7) ^ lr8;         // pre-swizzled source chunk

  const int kt0 = diag ? it * 2 : 0;
  const int nkt = K / 64;
  const int span = nkt - kt0;

  f32x4 acc[4][4];
  #pragma unroll
  for (int i = 0; i < 4; ++i)
    #pragma unroll
    for (int j = 0; j < 4; ++j) acc[i][j] = (f32x4)0.f;

  // stage one K-tile: A 128x64 (16KB) + B 128x64 (16KB); 8 gloads/thread
  auto stage = [&](int kt, int buf) {
    const size_t kb = (size_t)kt * 64 + schunk * 8;
    u16* la = &lds2[buf * 16384];
    u16* lb = la + 8192;
    #pragma unroll
    for (int u = 0; u < 4; ++u)
      gload16(A + (size_t)(m0 + u * 32 + w * 8 + lr8) * lda + kb,
              la + (u * 32 + w * 8) * 64);
    #pragma unroll
    for (int u = 0; u < 4; ++u)
      gload16(B + (size_t)(n0 + u * 32 + w * 8 + lr8) * ldb + kb,
              lb + (u * 32 + w * 8) * 64);
  };

  stage(kt0, 0);
  asm volatile("s_waitcnt vmcnt(0)" ::: "memory");
  __builtin_amdgcn_s_barrier();

  for (int t = 0; t < span; ++t) {
    const int buf = t & 1;
    if (t + 1 < span) stage(kt0 + t + 1, buf ^ 1);   // issue early, land late

    const u16* baseA = &lds2[buf * 16384];
    const u16* baseB = baseA + 8192;
    bf16x8 af[4][2], bv[4][2];
    #pragma unroll
    for (int mi = 0; mi < 4; ++mi) {
      int r = wm + mi * 16 + l15;
      #pragma unroll
      for (int kk = 0; kk < 2; ++kk) {
        int s = (kk * 4 + lhi) ^ (r & 7);
        af[mi][kk] = *reinterpret_cast<const bf16x8*>(&baseA[r * 64 + s * 8]);
      }
    }
    #pragma unroll
    for (int ni = 0; ni < 4; ++ni) {
      int r = wn + ni * 16 + l15;
      #pragma unroll
      for (int kk = 0; kk < 2; ++kk) {
        int s = (kk * 4 + lhi) ^ (r & 7);
        bv[ni][kk] = *reinterpret_cast<const bf16x8*>(&baseB[r * 64 + s * 8]);
      }
    }

    __builtin_amdgcn_s_setprio(1);
    #pragma unroll
    for (int kk = 0; kk < 2; ++kk)
      #pragma unroll
      for (int mi = 0; mi < 4; ++mi)
        #pragma unroll
        for (int ni = 0; ni < 4; ++ni)
          acc[mi][ni] = __builtin_amdgcn_mfma_f32_16x16x32_bf16(
              af[mi][kk], bv[ni][kk], acc[mi][ni], 0, 0, 0);
    __builtin_amdgcn_s_setprio(0);

    asm volatile("s_waitcnt vmcnt(0)" ::: "memory");  // t+1 landed (full iter cover)
    __builtin_amdgcn_s_barrier();
  }

  // epilogue: frag (mi,ni) -> row m0+wm+mi*16+lhi*4+q, col n0+wn+ni*16+l15
  if (EPI == 0) {
    u16* C = (u16*)Cv + (size_t)batch * cbs_;
    #pragma unroll
    for (int mi = 0; mi < 4; ++mi)
      #pragma unroll
      for (int q = 0; q < 4; ++q) {
        int row = m0 + wm + mi * 16 + lhi * 4 + q;
        u16* crow = C + (size_t)row * ldc + n0 + wn + l15;
        #pragma unroll
        for (int ni = 0; ni < 4; ++ni) crow[ni * 16] = f2bf(acc[mi][ni][q]);
      }
  } else if (EPI == 1) {
    u16* C = (u16*)Cv + (size_t)batch * cbs_;
    const float* ldp = ldec + (size_t)batch * 2048;
    float ldv[4];
    #pragma unroll
    for (int ni = 0; ni < 4; ++ni) ldv[ni] = ldp[n0 + wn + ni * 16 + l15];
    const float sc = 0.03125f;   // 1/sqrt(1024)
    #pragma unroll
    for (int mi = 0; mi < 4; ++mi)
      #pragma unroll
      for (int q = 0; q < 4; ++q) {
        int row = m0 + wm + mi * 16 + lhi * 4 + q;
        u16* crow = C + (size_t)row * ldc + n0 + wn + l15;
        #pragma unroll
        for (int ni = 0; ni < 4; ++ni) {
          int col = n0 + wn + ni * 16 + l15;
          int d = col - row;
          float wgt = (d > 0) ? expf(ldv[ni] * (float)(d - 1)) : 0.f;
          crow[ni * 16] = f2bf(acc[mi][ni][q] * sc * wgt);
        }
      }
  } else {
    float* C = (float*)Cv + (size_t)batch * cbs_;
    const float sc = scale_ptr[0];
    #pragma unroll
    for (int mi = 0; mi < 4; ++mi)
      #pragma unroll
      for (int q = 0; q < 4; ++q) {
        int row = m0 + wm + mi * 16 + lhi * 4 + q;
        float* crow = C + (size_t)row * ldc + n0 + wn + l15;
        #pragma unroll
        for (int ni = 0; ni < 4; ++ni) crow[ni * 16] = acc[mi][ni][q] * sc;
      }
  }
}

extern "C" void kernel_launch(void* const* d_in, const int* in_sizes, int n_in,
                              void* d_out, int out_size, void* d_ws, size_t ws_size,
                              hipStream_t stream) {
  const float* x   = (const float*)d_in[0];
  const float* Wq  = (const float*)d_in[1];
  const float* Wk  = (const float*)d_in[2];
  const float* Wv  = (const float*)d_in[3];
  const float* Wo  = (const float*)d_in[4];
  const float* Wd  = (const float*)d_in[5];
  const float* bd  = (const float*)d_in[6];
  const float* osc = (const float*)d_in[7];
  float* out = (float*)d_out;

  char* ws = (char*)d_ws;
  size_t off = 0;
  u16* Xbf  = (u16*)(ws + off); off += (size_t)8192 * 1024 * 2;
  u16* Wall = (u16*)(ws + off); off += (size_t)4096 * 1024 * 2;
  u16* VT   = (u16*)(ws + off); off += (size_t)1024 * 8192 * 2;
  u16* S    = (u16*)(ws + off); off += (size_t)4 * 2048 * 2048 * 2;
  float* ldec = (float*)(ws + off); off += (size_t)8192 * 4;
  u16* QK   = (u16*)(ws + off); off += (size_t)8192 * 2048 * 2;
  u16* R    = QK;  // alias: QK dead once S built

  u16* Wqk = Wall;
  u16* Wvb = Wall + 2 * 1048576;
  u16* Wob = Wall + 3 * 1048576;

  // 1) merged prep: x cast + decay + weight casts
  prep<<<12288, 256, 0, stream>>>(x, Xbf, Wd, bd, ldec, Wq, Wk, Wv, Wo, Wall);

  // 2) QK = Xbf @ Wqk^T  [8192 x 2048]  (1024 blocks, 4/CU)
  gemmP<0><<<dim3(64 * 16, 1), 256, 0, stream>>>(
      Xbf, Wqk, QK, 1024, 1024, 2048, 1024, 16, 0, 0, nullptr, nullptr,
      0, 0, 0);

  // 3) VT = Wvb @ Xbf^T  [1024 x 8192]  (512 blocks, 2/CU)
  gemmP<0><<<dim3(8 * 64, 1), 256, 0, stream>>>(
      Wvb, Xbf, VT, 1024, 1024, 8192, 1024, 64, 0, 0, nullptr, nullptr,
      0, 0, 0);

  // 4) S_b = (Q_b K_b^T /32) ∘ weights -> bf16  (544 live of 1024)
  gemmP<1><<<dim3(16 * 16, 4), 256, 0, stream>>>(
      QK, QK + 1024, S, 2048, 2048, 2048, 1024, 16, 0, 0, ldec, nullptr,
      4194304LL, 4194304LL, 4194304LL);

  // 5) R_b = S_b @ V_b  [2048 x 1024], kt0=2it, batch-parity flip  (512 blocks)
  gemmP<0><<<dim3(16 * 8, 4), 256, 0, stream>>>(
      S, VT, R, 2048, 8192, 1024, 2048, 8, 1, 1, nullptr, nullptr,
      4194304LL, 2048LL, 2097152LL);

  // 6) out = R @ Wo^T * out_scale  [8192 x 1024] fp32  (512 blocks)
  gemmP<2><<<dim3(64 * 8, 1), 256, 0, stream>>>(
      R, Wob, out, 1024, 1024, 1024, 1024, 8, 0, 0, nullptr, osc,
      0, 0, 0);
}